// Round 3
// baseline (152.878 us; speedup 1.0000x reference)
//
#include <hip/hip_runtime.h>

// LSTM(units=64) over T=5, D_IN=1, then Dense(1, relu).  R3.
// fp16 MFMA for h@U (fp32 acc); gates in fp32 via exp2 + SHARED rcp:
//   i*g       = (1-e_g) * rcp((1+e_i)(1+e_g))      e_x = exp2(scaled z)
//   o*tanh(c) = (1-e_c) * rcp((1+e_o)(1+e_c))
// -> 5 exp2 + 3 rcp per cell (was 5+5).
// R1/R2 lesson (VGPR=60 both rounds): the compiler SINKS the global-U
// load+scale+cvt chain into the t-loop (legal clone of const loads),
// re-executing ~224 VALU instrs per timestep. Fix: stage scaled f16
// B-fragments in LDS once, read them ONCE into Bf[4][2], and pin with
// empty inline-asm so the loads cannot be re-sunk.
// Block = 256 threads (4 waves) = 64 batch rows; wave w owns gate-cols
// [w*16,w*16+16) of all 4 gates. h round-trips LDS f16 (stride 72);
// c stays in regs in MFMA C/D layout (col=lane&15, row=quad*4+reg).

typedef _Float16 f16x8 __attribute__((ext_vector_type(8)));
typedef float f32x4 __attribute__((ext_vector_type(4)));

#define MB 64
#define NTHREADS 256
#define HSTR 72

__device__ __forceinline__ float ex2(float x) { return __builtin_amdgcn_exp2f(x); }
__device__ __forceinline__ float rcp(float x) { return __builtin_amdgcn_rcpf(x); }

__global__ __launch_bounds__(NTHREADS, 2) void lstm_fused(
    const float* __restrict__ x,   // [B,5,1]
    const float* __restrict__ W,   // [1,256]  gate order i,f,g,o
    const float* __restrict__ U,   // [64,256]
    const float* __restrict__ b,   // [256]
    const float* __restrict__ Wd,  // [64,1]
    const float* __restrict__ bd,  // [1]
    float* __restrict__ out,       // [B,1]
    int B)
{
    __shared__ _Float16 hbuf[2][64 * HSTR];   // 18.4 KB
    __shared__ f16x8 ufrag[4 * 4 * 2 * 64];   // 32 KB: [wv][g][kh][lane]
    __shared__ float xs[MB * 5];              // 1.25 KB
    __shared__ float red[4][64];              // 1 KB

    const int tid  = threadIdx.x;
    const int wv   = tid >> 6;
    const int lane = tid & 63;
    const int l15  = lane & 15;
    const int quad = lane >> 4;
    const int row0 = blockIdx.x * MB;

    for (int i = tid; i < MB * 5; i += NTHREADS) xs[i] = x[row0 * 5 + i];

    const float LOG2E = 1.44269504f;
    // sigmoid gates scaled by -log2e: sigma(z) = rcp(1+exp2(-L z)).
    // tanh gate scaled by -2log2e:    tanh(z)  = (1-e)/(1+e), e=exp2(-2L z).
    const float gscale[4] = {-LOG2E, -LOG2E, -2.0f * LOG2E, -LOG2E};
    const float CSC = -2.0f * LOG2E;   // scale for tanh(c)

    // Build scaled f16 U B-fragments (n = gate*64 + wv*16 + l15,
    // k = kh*32 + quad*8 + j) and park them in LDS so the per-timestep
    // "reload" (if the compiler insists) is ds_read_b128, not 28 VALU ops.
    const int ncol = wv * 16 + l15;
    float Wf[4], bf[4];
#pragma unroll
    for (int g = 0; g < 4; ++g) {
        const int n = g * 64 + ncol;
        const float s = gscale[g];
        Wf[g] = W[n] * s;
        bf[g] = b[n] * s;
#pragma unroll
        for (int kh = 0; kh < 2; ++kh) {
            f16x8 v;
#pragma unroll
            for (int j = 0; j < 8; ++j) {
                const int k = kh * 32 + quad * 8 + j;
                v[j] = (_Float16)(U[k * 256 + n] * s);
            }
            ufrag[((wv * 4 + g) * 2 + kh) * 64 + lane] = v;
        }
    }

    float c[4][4];
#pragma unroll
    for (int a = 0; a < 4; ++a)
#pragma unroll
        for (int r = 0; r < 4; ++r) c[a][r] = 0.0f;

    __syncthreads();  // xs + ufrag visible (ufrag is own-lane data anyway)

    // ---- t = 0 (h=0, c=0): c = i*g, h = o*tanh(c) ----
#pragma unroll
    for (int rt = 0; rt < 4; ++rt) {
#pragma unroll
        for (int r = 0; r < 4; ++r) {
            const int rloc = rt * 16 + quad * 4 + r;
            const float xv = xs[rloc * 5 + 0];
            const float ei = ex2(__builtin_fmaf(xv, Wf[0], bf[0]));
            const float eg = ex2(__builtin_fmaf(xv, Wf[2], bf[2]));
            const float eo = ex2(__builtin_fmaf(xv, Wf[3], bf[3]));
            const float r1 = rcp((1.0f + ei) * (1.0f + eg));
            const float cn = (1.0f - eg) * r1;            // i*g
            c[rt][r] = cn;
            const float ec = ex2(cn * CSC);
            const float r2 = rcp((1.0f + eo) * (1.0f + ec));
            hbuf[0][rloc * HSTR + ncol] = (_Float16)((1.0f - ec) * r2);
        }
    }

    // Load B-fragments ONCE; pin so they can't be re-sunk into the loop.
    f16x8 Bf[4][2];
#pragma unroll
    for (int g = 0; g < 4; ++g)
#pragma unroll
        for (int kh = 0; kh < 2; ++kh) {
            Bf[g][kh] = ufrag[((wv * 4 + g) * 2 + kh) * 64 + lane];
            asm volatile("" : "+v"(Bf[g][kh]));
        }

    // ---- t = 1..4 ----
#pragma unroll
    for (int t = 1; t < 5; ++t) {
        const int src = (t + 1) & 1;
        const int dst = t & 1;
        __syncthreads();
#pragma unroll
        for (int rt = 0; rt < 4; ++rt) {
            const int arow = rt * 16 + l15;   // A layout: m = lane&15
            const f16x8 a0 = *(const f16x8*)&hbuf[src][arow * HSTR + quad * 8];
            const f16x8 a1 = *(const f16x8*)&hbuf[src][arow * HSTR + 32 + quad * 8];
            float xv[4];
#pragma unroll
            for (int r = 0; r < 4; ++r)
                xv[r] = xs[(rt * 16 + quad * 4 + r) * 5 + t];
            f32x4 acc[4];
#pragma unroll
            for (int g = 0; g < 4; ++g) {
                f32x4 z;
#pragma unroll
                for (int r = 0; r < 4; ++r)
                    z[r] = __builtin_fmaf(xv[r], Wf[g], bf[g]);
                z = __builtin_amdgcn_mfma_f32_16x16x32_f16(a0, Bf[g][0], z, 0, 0, 0);
                z = __builtin_amdgcn_mfma_f32_16x16x32_f16(a1, Bf[g][1], z, 0, 0, 0);
                acc[g] = z;
            }
#pragma unroll
            for (int r = 0; r < 4; ++r) {
                const int rloc = rt * 16 + quad * 4 + r;
                const float ei = ex2(acc[0][r]);
                const float ef = ex2(acc[1][r]);
                const float eg = ex2(acc[2][r]);
                const float eo = ex2(acc[3][r]);
                const float r1 = rcp((1.0f + ei) * (1.0f + eg));
                const float fg = rcp(1.0f + ef);
                const float ig = (1.0f - eg) * r1;
                const float cn = __builtin_fmaf(fg, c[rt][r], ig);
                c[rt][r] = cn;
                const float ec = ex2(cn * CSC);
                const float r2 = rcp((1.0f + eo) * (1.0f + ec));
                hbuf[dst][rloc * HSTR + ncol] = (_Float16)((1.0f - ec) * r2);
            }
        }
    }

    __syncthreads();  // h(t=4) complete in hbuf[0]

    // Dense(1, relu)
    {
        const int row = tid & 63;
        const int q   = tid >> 6;
        float s = 0.0f;
#pragma unroll
        for (int j = 0; j < 16; ++j)
            s += (float)hbuf[0][row * HSTR + q * 16 + j] * Wd[q * 16 + j];
        red[q][row] = s;
    }
    __syncthreads();
    if (tid < 64) {
        const float r = red[0][tid] + red[1][tid] + red[2][tid] + red[3][tid] + bd[0];
        out[row0 + tid] = fmaxf(r, 0.0f);
    }
}

extern "C" void kernel_launch(void* const* d_in, const int* in_sizes, int n_in,
                              void* d_out, int out_size, void* d_ws, size_t ws_size,
                              hipStream_t stream) {
    const float* x  = (const float*)d_in[0];
    const float* W  = (const float*)d_in[1];
    const float* U  = (const float*)d_in[2];
    const float* b  = (const float*)d_in[3];
    const float* Wd = (const float*)d_in[4];
    const float* bd = (const float*)d_in[5];
    float* out = (float*)d_out;
    const int B = in_sizes[0] / 5;
    const int grid = B / MB;   // 4096 blocks
    lstm_fused<<<grid, NTHREADS, 0, stream>>>(x, W, U, b, Wd, bd, out, B);
}

// Round 4
// 148.619 us; speedup vs baseline: 1.0287x; 1.0287x over previous
//
#include <hip/hip_runtime.h>

// LSTM(units=64) over T=5, D_IN=1, then Dense(1, relu).  R4.
// fp16 MFMA for h@U (fp32 acc); gates via exp2 + shared/merged rcp:
//   p=(1+ei)(1+eg), q=(1+ef):  c' = (c*p + q*(1-eg)) * rcp(p*q)
//   h = o*tanh(c') = (1-ec) * rcp((1+eo)(1+ec)),  ec = exp2(-2L*c')
// -> 5 exp2 + 2 rcp per cell.
// R3 post-mortem: asm-pin DOES hold Bf resident (VGPR 68, issue -11%),
// but the 32KB LDS staging buffer capped occupancy at 3 blocks/CU and
// regressed. R4 = pin-only (no ufrag), LDS back to ~20.7KB.
// xs stored transposed [t][row] so per-rt x reads are one broadcast
// ds_read_b128 instead of 4 scalar reads.
// Block = 256 threads (4 waves) = 64 batch rows; wave w owns gate-cols
// [w*16,w*16+16) of all 4 gates -> U B-fragments live in 32 VGPRs.
// h round-trips LDS f16 (stride 72); c in regs in C/D layout
// (col=lane&15, row=quad*4+reg — m89-verified mapping).

typedef _Float16 f16x8 __attribute__((ext_vector_type(8)));
typedef float f32x4 __attribute__((ext_vector_type(4)));

#define MB 64
#define NTHREADS 256
#define HSTR 72

__device__ __forceinline__ float ex2(float x) { return __builtin_amdgcn_exp2f(x); }
__device__ __forceinline__ float rcp(float x) { return __builtin_amdgcn_rcpf(x); }

__global__ __launch_bounds__(NTHREADS, 2) void lstm_fused(
    const float* __restrict__ x,   // [B,5,1]
    const float* __restrict__ W,   // [1,256]  gate order i,f,g,o
    const float* __restrict__ U,   // [64,256]
    const float* __restrict__ b,   // [256]
    const float* __restrict__ Wd,  // [64,1]
    const float* __restrict__ bd,  // [1]
    float* __restrict__ out,       // [B,1]
    int B)
{
    __shared__ _Float16 hbuf[2][64 * HSTR];   // 18.0 KB
    __shared__ float xs[5][64];               // 1.25 KB, [t][row]
    __shared__ float red[4][64];              // 1 KB

    const int tid  = threadIdx.x;
    const int wv   = tid >> 6;
    const int lane = tid & 63;
    const int l15  = lane & 15;
    const int quad = lane >> 4;
    const int row0 = blockIdx.x * MB;

    // stage x, transposed to [t][row] (coalesced read, scattered write)
    for (int i = tid; i < MB * 5; i += NTHREADS)
        xs[i % 5][i / 5] = x[row0 * 5 + i];

    const float LOG2E = 1.44269504f;
    // sigmoid gates scaled by -log2e: sigma(z) = rcp(1+exp2(-L z))
    // tanh gate scaled by -2log2e:    tanh(z)  = (1-e)/(1+e), e=exp2(-2L z)
    const float gscale[4] = {-LOG2E, -LOG2E, -2.0f * LOG2E, -LOG2E};
    const float CSC = -2.0f * LOG2E;

    // U B-fragments loaded ONCE (n = gate*64 + wv*16 + l15,
    // k = kh*32 + quad*8 + j), scaled, cvt to f16, then pinned with
    // volatile asm so the load/scale/cvt chain cannot be sunk into the
    // t-loop (R1/R2 remat pathology).
    const int ncol = wv * 16 + l15;
    float Wf[4], bf[4];
    f16x8 Bf[4][2];
#pragma unroll
    for (int g = 0; g < 4; ++g) {
        const int n = g * 64 + ncol;
        const float s = gscale[g];
        Wf[g] = W[n] * s;
        bf[g] = b[n] * s;
#pragma unroll
        for (int kh = 0; kh < 2; ++kh) {
            f16x8 v;
#pragma unroll
            for (int j = 0; j < 8; ++j) {
                const int k = kh * 32 + quad * 8 + j;
                v[j] = (_Float16)(U[k * 256 + n] * s);
            }
            Bf[g][kh] = v;
            asm volatile("" : "+v"(Bf[g][kh]));
        }
    }

    float c[4][4];
#pragma unroll
    for (int a = 0; a < 4; ++a)
#pragma unroll
        for (int r = 0; r < 4; ++r) c[a][r] = 0.0f;

    __syncthreads();  // xs visible

    // ---- t = 0 (h=0, c=0): c = i*g, h = o*tanh(c) ----
#pragma unroll
    for (int rt = 0; rt < 4; ++rt) {
        const f32x4 xv = *(const f32x4*)&xs[0][rt * 16 + quad * 4];
#pragma unroll
        for (int r = 0; r < 4; ++r) {
            const int rloc = rt * 16 + quad * 4 + r;
            const float ei = ex2(__builtin_fmaf(xv[r], Wf[0], bf[0]));
            const float eg = ex2(__builtin_fmaf(xv[r], Wf[2], bf[2]));
            const float eo = ex2(__builtin_fmaf(xv[r], Wf[3], bf[3]));
            const float r1 = rcp((1.0f + ei) * (1.0f + eg));
            const float cn = (1.0f - eg) * r1;            // i*g
            c[rt][r] = cn;
            const float ec = ex2(cn * CSC);
            const float r2 = rcp((1.0f + eo) * (1.0f + ec));
            hbuf[0][rloc * HSTR + ncol] = (_Float16)((1.0f - ec) * r2);
        }
    }

    // ---- t = 1..4 ----
#pragma unroll
    for (int t = 1; t < 5; ++t) {
        const int src = (t + 1) & 1;
        const int dst = t & 1;
        __syncthreads();
#pragma unroll
        for (int rt = 0; rt < 4; ++rt) {
            const int arow = rt * 16 + l15;   // A layout: m = lane&15
            const f16x8 a0 = *(const f16x8*)&hbuf[src][arow * HSTR + quad * 8];
            const f16x8 a1 = *(const f16x8*)&hbuf[src][arow * HSTR + 32 + quad * 8];
            const f32x4 xv = *(const f32x4*)&xs[t][rt * 16 + quad * 4];
            f32x4 acc[4];
#pragma unroll
            for (int g = 0; g < 4; ++g) {
                f32x4 z;
#pragma unroll
                for (int r = 0; r < 4; ++r)
                    z[r] = __builtin_fmaf(xv[r], Wf[g], bf[g]);
                z = __builtin_amdgcn_mfma_f32_16x16x32_f16(a0, Bf[g][0], z, 0, 0, 0);
                z = __builtin_amdgcn_mfma_f32_16x16x32_f16(a1, Bf[g][1], z, 0, 0, 0);
                acc[g] = z;
            }
#pragma unroll
            for (int r = 0; r < 4; ++r) {
                const int rloc = rt * 16 + quad * 4 + r;
                const float ei = ex2(acc[0][r]);
                const float ef = ex2(acc[1][r]);
                const float eg = ex2(acc[2][r]);
                const float eo = ex2(acc[3][r]);
                const float p  = (1.0f + ei) * (1.0f + eg);
                const float q  = 1.0f + ef;
                const float num = __builtin_fmaf(c[rt][r], p, q * (1.0f - eg));
                const float cn  = num * rcp(p * q);
                c[rt][r] = cn;
                const float ec = ex2(cn * CSC);
                const float r2 = rcp((1.0f + eo) * (1.0f + ec));
                hbuf[dst][rloc * HSTR + ncol] = (_Float16)((1.0f - ec) * r2);
            }
        }
    }

    __syncthreads();  // h(t=4) complete in hbuf[0]

    // Dense(1, relu)
    {
        const int row = tid & 63;
        const int q   = tid >> 6;
        float s = 0.0f;
#pragma unroll
        for (int j = 0; j < 16; ++j)
            s += (float)hbuf[0][row * HSTR + q * 16 + j] * Wd[q * 16 + j];
        red[q][row] = s;
    }
    __syncthreads();
    if (tid < 64) {
        const float r = red[0][tid] + red[1][tid] + red[2][tid] + red[3][tid] + bd[0];
        out[row0 + tid] = fmaxf(r, 0.0f);
    }
}

extern "C" void kernel_launch(void* const* d_in, const int* in_sizes, int n_in,
                              void* d_out, int out_size, void* d_ws, size_t ws_size,
                              hipStream_t stream) {
    const float* x  = (const float*)d_in[0];
    const float* W  = (const float*)d_in[1];
    const float* U  = (const float*)d_in[2];
    const float* b  = (const float*)d_in[3];
    const float* Wd = (const float*)d_in[4];
    const float* bd = (const float*)d_in[5];
    float* out = (float*)d_out;
    const int B = in_sizes[0] / 5;
    const int grid = B / MB;   // 4096 blocks
    lstm_fused<<<grid, NTHREADS, 0, stream>>>(x, W, U, b, Wd, bd, out, B);
}

// Round 5
// 146.091 us; speedup vs baseline: 1.0465x; 1.0173x over previous
//
#include <hip/hip_runtime.h>

// LSTM(units=64) over T=5, D_IN=1, then Dense(1, relu).  R5.
// fp16 MFMA for h@U (fp32 acc); gates via exp2 + merged rcp:
//   p=(1+ei)(1+eg), q=(1+ef):  c' = (c*p + q*(1-eg)) * rcp(p*q)
//   h = o*tanh(c') = (1-ec) * rcp((1+eo)(1+ec)),  ec = exp2(-2L*c')
// 5 exp2 + 2 rcp per cell; measured trans issue ~16 cyc/wave64 ->
// trans dominates (112 of ~144 cyc/cell). Kernel is ~95% of its issue
// floor at 79% wall utilization (R4).
// R4 finding: residency pinned ~3 blocks/CU (12 waves) independent of
// LDS (21KB R4 vs 53KB R3 both ~12 waves) -> register-budget pin
// (Bf parked in AGPRs, unified file). So LDS<=~50KB is free.
// R5: MB=128 = TWO 64-row groups per 4-wave block. Doubles post-barrier
// independent work (8 rt-tiles) to fill the 21% idle, halves grid, and
// amortizes the U-fragment preamble (~10-15% of wave cycles) over 2x
// rows. Math unchanged (absmax must hold at 1.95e-3).
// Wave w owns gate-cols [w*16,w*16+16) of all 4 gates; Bf pinned via
// volatile asm (R1/R2 remat pathology). h via LDS f16 (stride 72);
// c in regs in C/D layout (col=lane&15, row=quad*4+reg).

typedef _Float16 f16x8 __attribute__((ext_vector_type(8)));
typedef float f32x4 __attribute__((ext_vector_type(4)));

#define MB 128       // rows per block (2 groups of 64)
#define NTHREADS 256
#define HSTR 72

__device__ __forceinline__ float ex2(float x) { return __builtin_amdgcn_exp2f(x); }
__device__ __forceinline__ float rcp(float x) { return __builtin_amdgcn_rcpf(x); }

__global__ __launch_bounds__(NTHREADS, 2) void lstm_fused(
    const float* __restrict__ x,   // [B,5,1]
    const float* __restrict__ W,   // [1,256]  gate order i,f,g,o
    const float* __restrict__ U,   // [64,256]
    const float* __restrict__ b,   // [256]
    const float* __restrict__ Wd,  // [64,1]
    const float* __restrict__ bd,  // [1]
    float* __restrict__ out,       // [B,1]
    int B)
{
    __shared__ _Float16 hbuf[2][2][64 * HSTR];  // [group][parity] 36.9 KB
    __shared__ float xs[5][MB];                 // 2.5 KB, [t][row]
    __shared__ float red[2][MB];                // 1 KB
    __shared__ float wds[64];                   // 0.25 KB

    const int tid  = threadIdx.x;
    const int wv   = tid >> 6;
    const int lane = tid & 63;
    const int l15  = lane & 15;
    const int quad = lane >> 4;
    const int row0 = blockIdx.x * MB;

    // stage x transposed to [t][row]; stage Wd
    for (int i = tid; i < MB * 5; i += NTHREADS)
        xs[i % 5][i / 5] = x[row0 * 5 + i];
    if (tid < 64) wds[tid] = Wd[tid];

    const float LOG2E = 1.44269504f;
    const float gscale[4] = {-LOG2E, -LOG2E, -2.0f * LOG2E, -LOG2E};
    const float CSC = -2.0f * LOG2E;

    // U B-fragments loaded ONCE (n = gate*64 + wv*16 + l15,
    // k = kh*32 + quad*8 + j), scaled, cvt f16, pinned vs remat.
    const int ncol = wv * 16 + l15;
    float Wf[4], bf[4];
    f16x8 Bf[4][2];
#pragma unroll
    for (int g = 0; g < 4; ++g) {
        const int n = g * 64 + ncol;
        const float s = gscale[g];
        Wf[g] = W[n] * s;
        bf[g] = b[n] * s;
#pragma unroll
        for (int kh = 0; kh < 2; ++kh) {
            f16x8 v;
#pragma unroll
            for (int j = 0; j < 8; ++j) {
                const int k = kh * 32 + quad * 8 + j;
                v[j] = (_Float16)(U[k * 256 + n] * s);
            }
            Bf[g][kh] = v;
            asm volatile("" : "+v"(Bf[g][kh]));
        }
    }

    float c[2][4][4];
#pragma unroll
    for (int gr = 0; gr < 2; ++gr)
#pragma unroll
        for (int a = 0; a < 4; ++a)
#pragma unroll
            for (int r = 0; r < 4; ++r) c[gr][a][r] = 0.0f;

    __syncthreads();  // xs visible

    // ---- t = 0 (h=0, c=0): c = i*g, h = o*tanh(c) ----
#pragma unroll
    for (int gr = 0; gr < 2; ++gr) {
#pragma unroll
        for (int rt = 0; rt < 4; ++rt) {
            const f32x4 xv = *(const f32x4*)&xs[0][gr * 64 + rt * 16 + quad * 4];
#pragma unroll
            for (int r = 0; r < 4; ++r) {
                const int rloc = rt * 16 + quad * 4 + r;
                const float ei = ex2(__builtin_fmaf(xv[r], Wf[0], bf[0]));
                const float eg = ex2(__builtin_fmaf(xv[r], Wf[2], bf[2]));
                const float eo = ex2(__builtin_fmaf(xv[r], Wf[3], bf[3]));
                const float r1 = rcp((1.0f + ei) * (1.0f + eg));
                const float cn = (1.0f - eg) * r1;            // i*g
                c[gr][rt][r] = cn;
                const float ec = ex2(cn * CSC);
                const float r2 = rcp((1.0f + eo) * (1.0f + ec));
                hbuf[gr][0][rloc * HSTR + ncol] = (_Float16)((1.0f - ec) * r2);
            }
        }
    }

    // ---- t = 1..4 ----
#pragma unroll
    for (int t = 1; t < 5; ++t) {
        const int src = (t + 1) & 1;
        const int dst = t & 1;
        __syncthreads();
#pragma unroll
        for (int gr = 0; gr < 2; ++gr) {
#pragma unroll
            for (int rt = 0; rt < 4; ++rt) {
                const int arow = rt * 16 + l15;   // A layout: m = lane&15
                const f16x8 a0 = *(const f16x8*)&hbuf[gr][src][arow * HSTR + quad * 8];
                const f16x8 a1 = *(const f16x8*)&hbuf[gr][src][arow * HSTR + 32 + quad * 8];
                const f32x4 xv = *(const f32x4*)&xs[t][gr * 64 + rt * 16 + quad * 4];
                f32x4 acc[4];
#pragma unroll
                for (int g = 0; g < 4; ++g) {
                    f32x4 z;
#pragma unroll
                    for (int r = 0; r < 4; ++r)
                        z[r] = __builtin_fmaf(xv[r], Wf[g], bf[g]);
                    z = __builtin_amdgcn_mfma_f32_16x16x32_f16(a0, Bf[g][0], z, 0, 0, 0);
                    z = __builtin_amdgcn_mfma_f32_16x16x32_f16(a1, Bf[g][1], z, 0, 0, 0);
                    acc[g] = z;
                }
#pragma unroll
                for (int r = 0; r < 4; ++r) {
                    const int rloc = rt * 16 + quad * 4 + r;
                    const float ei = ex2(acc[0][r]);
                    const float ef = ex2(acc[1][r]);
                    const float eg = ex2(acc[2][r]);
                    const float eo = ex2(acc[3][r]);
                    const float p  = (1.0f + ei) * (1.0f + eg);
                    const float q  = 1.0f + ef;
                    const float num = __builtin_fmaf(c[gr][rt][r], p, q * (1.0f - eg));
                    const float cn  = num * rcp(p * q);
                    c[gr][rt][r] = cn;
                    const float ec = ex2(cn * CSC);
                    const float r2 = rcp((1.0f + eo) * (1.0f + ec));
                    hbuf[gr][dst][rloc * HSTR + ncol] = (_Float16)((1.0f - ec) * r2);
                }
            }
        }
    }

    __syncthreads();  // h(t=4) complete in hbuf[*][0]

    // Dense(1, relu): each thread sums 32 of the 64 units for one row.
    {
        const int row = tid & 127;          // 0..127
        const int qh  = tid >> 7;           // 0..1
        const int gr  = row >> 6;
        const int rl  = row & 63;
        float s = 0.0f;
#pragma unroll
        for (int j = 0; j < 32; ++j)
            s += (float)hbuf[gr][0][rl * HSTR + qh * 32 + j] * wds[qh * 32 + j];
        red[qh][row] = s;
    }
    __syncthreads();
    if (tid < MB) {
        const float r = red[0][tid] + red[1][tid] + bd[0];
        out[row0 + tid] = fmaxf(r, 0.0f);
    }
}

extern "C" void kernel_launch(void* const* d_in, const int* in_sizes, int n_in,
                              void* d_out, int out_size, void* d_ws, size_t ws_size,
                              hipStream_t stream) {
    const float* x  = (const float*)d_in[0];
    const float* W  = (const float*)d_in[1];
    const float* U  = (const float*)d_in[2];
    const float* b  = (const float*)d_in[3];
    const float* Wd = (const float*)d_in[4];
    const float* bd = (const float*)d_in[5];
    float* out = (float*)d_out;
    const int B = in_sizes[0] / 5;
    const int grid = B / MB;   // 262144/128 = 2048 blocks
    lstm_fused<<<grid, NTHREADS, 0, stream>>>(x, W, U, b, Wd, bd, out, B);
}